// Round 7
// baseline (168.709 us; speedup 1.0000x reference)
//
#include <hip/hip_runtime.h>
#include <hip/hip_bf16.h>

#define N_NODES 4096
#define DIN     512
#define FDIM    64
#define NHEADS  8
#define DOUT    16
#define MAXN    512

typedef __attribute__((ext_vector_type(8))) short bf16x8;
typedef __attribute__((ext_vector_type(4))) float f32x4;

static __device__ __forceinline__ float us2f(unsigned short u) {
    union { unsigned int i; float f; } cv; cv.i = ((unsigned int)u) << 16; return cv.f;
}
static __device__ __forceinline__ unsigned short f2us(float v) {
    __hip_bfloat16 b = __float2bfloat16(v);
    return *(const unsigned short*)&b;
}
// dtype: adj[0][0] is a guaranteed self-loop 1.0; fp32 1.0f low ushort = 0 (verified r4-r11)
static __device__ __forceinline__ int is_f32(const void* adj) {
    return (((const unsigned short*)adj)[0] == 0) ? 1 : 0;
}

// ---------------------------------------------------------------------------
// K0: STANDALONE ballot scan, wave-per-row, NO LDS (occupancy = reg-bound only).
// Loads in batches of 8 uint4 (32 VGPRs data, ~8 KB/wave in flight) so the
// allocator can actually keep them in flight (r6's 16-deep buffer was silently
// re-interleaved at VGPR_Count=68). 1024 blocks x 4 waves.
// ---------------------------------------------------------------------------
__global__ __launch_bounds__(256) void scan_kernel(
    const void* __restrict__ adj, int* __restrict__ cnt, int* __restrict__ nbr)
{
    const int wv   = threadIdx.x >> 6;
    const int lane = threadIdx.x & 63;
    const int n = blockIdx.x * 4 + wv;
    const unsigned long long lmask = (1ull << lane) - 1ull;
    int c = 0;
    int* nrow = nbr + (size_t)n * MAXN;
    if (is_f32(adj)) {
        const uint4* row = (const uint4*)((const unsigned int*)adj + (size_t)n * N_NODES);
#pragma unroll
        for (int batch = 0; batch < 2; ++batch) {
            uint4 vb[8];
#pragma unroll
            for (int i = 0; i < 8; ++i) vb[i] = row[(batch * 8 + i) * 64 + lane];
#pragma unroll
            for (int i = 0; i < 8; ++i) {
                uint4 v = vb[i];
                int base = ((batch * 8 + i) * 64 + lane) * 4;
                unsigned long long m0 = __ballot(v.x != 0u);
                unsigned long long m1 = __ballot(v.y != 0u);
                unsigned long long m2 = __ballot(v.z != 0u);
                unsigned long long m3 = __ballot(v.w != 0u);
                int p;
                p = c + __popcll(m0 & lmask); if (v.x && p < MAXN) nrow[p] = base + 0; c += __popcll(m0);
                p = c + __popcll(m1 & lmask); if (v.y && p < MAXN) nrow[p] = base + 1; c += __popcll(m1);
                p = c + __popcll(m2 & lmask); if (v.z && p < MAXN) nrow[p] = base + 2; c += __popcll(m2);
                p = c + __popcll(m3 & lmask); if (v.w && p < MAXN) nrow[p] = base + 3; c += __popcll(m3);
            }
        }
    } else {
        const ushort4* row = (const ushort4*)((const unsigned short*)adj + (size_t)n * N_NODES);
#pragma unroll
        for (int batch = 0; batch < 2; ++batch) {
            ushort4 vb[8];
#pragma unroll
            for (int i = 0; i < 8; ++i) vb[i] = row[(batch * 8 + i) * 64 + lane];
#pragma unroll
            for (int i = 0; i < 8; ++i) {
                ushort4 v = vb[i];
                int base = ((batch * 8 + i) * 64 + lane) * 4;
                unsigned long long m0 = __ballot(v.x != 0);
                unsigned long long m1 = __ballot(v.y != 0);
                unsigned long long m2 = __ballot(v.z != 0);
                unsigned long long m3 = __ballot(v.w != 0);
                int p;
                p = c + __popcll(m0 & lmask); if (v.x && p < MAXN) nrow[p] = base + 0; c += __popcll(m0);
                p = c + __popcll(m1 & lmask); if (v.y && p < MAXN) nrow[p] = base + 1; c += __popcll(m1);
                p = c + __popcll(m2 & lmask); if (v.z && p < MAXN) nrow[p] = base + 2; c += __popcll(m2);
                p = c + __popcll(m3 & lmask); if (v.w && p < MAXN) nrow[p] = base + 3; c += __popcll(m3);
            }
        }
    }
    if (lane == 0) cnt[n] = (c < MAXN) ? c : MAXN;
}

// ---------------------------------------------------------------------------
// K1: prep. Blocks 0..63: W -> Wt[h][f][d] bf16 via LDS 64x64 tile transpose.
// Blocks 64..71: Woc/vecs. (verified r5/r6)
// ---------------------------------------------------------------------------
__global__ __launch_bounds__(256) void prep_kernel(
    const void* __restrict__ adj, const void* __restrict__ W,
    const void* __restrict__ a1, const void* __restrict__ a2, const void* __restrict__ Wo,
    const void* __restrict__ ao1, const void* __restrict__ ao2,
    unsigned short* __restrict__ Wt, float* __restrict__ Woc,
    float* __restrict__ a1c, float* __restrict__ a2c,
    float* __restrict__ ao1c, float* __restrict__ ao2c)
{
    const int f32 = is_f32(adj);
    const int b = blockIdx.x;
    const int t = threadIdx.x;
    if (b < 64) {
        const int h  = b >> 3;
        const int d0 = (b & 7) * 64;
        __shared__ float tile[64][65];
        const size_t wbase = (size_t)h * DIN * FDIM + (size_t)d0 * FDIM;
#pragma unroll
        for (int pass = 0; pass < 16; ++pass) {
            int i = pass * 256 + t;
            int dl = i >> 6, f = i & 63;
            float v = f32 ? ((const float*)W)[wbase + dl * FDIM + f]
                          : us2f(((const unsigned short*)W)[wbase + dl * FDIM + f]);
            tile[dl][f] = v;
        }
        __syncthreads();
#pragma unroll
        for (int pass = 0; pass < 16; ++pass) {
            int i = pass * 256 + t;
            int f = i >> 6, dl = i & 63;
            Wt[((size_t)(h * FDIM + f)) * DIN + d0 + dl] = f2us(tile[dl][f]);
        }
        return;
    }
    const int i0 = (b - 64) * 256 + t;   // [0, 2048)
    for (int i = i0; i < DIN * DOUT; i += 2048) {
        float v = f32 ? ((const float*)Wo)[i] : us2f(((const unsigned short*)Wo)[i]);
        Woc[i] = v;   // row-major [d][j], fp32
    }
    if (i0 < 512) {
        a1c[i0] = f32 ? ((const float*)a1)[i0] : us2f(((const unsigned short*)a1)[i0]);
        a2c[i0] = f32 ? ((const float*)a2)[i0] : us2f(((const unsigned short*)a2)[i0]);
    }
    if (i0 < 16) {
        ao1c[i0] = f32 ? ((const float*)ao1)[i0] : us2f(((const unsigned short*)ao1)[i0]);
        ao2c[i0] = f32 ? ((const float*)ao2)[i0] : us2f(((const unsigned short*)ao2)[i0]);
    }
}

// ---------------------------------------------------------------------------
// K2: STANDALONE split-K MFMA wh (2048 blocks; math verified r4-r6).
// Separate kernel so rocprof attributes its cost exactly.
// ---------------------------------------------------------------------------
__global__ __launch_bounds__(256) void wh_kernel(
    const void* __restrict__ adj, const void* __restrict__ X,
    const unsigned short* __restrict__ Wt,
    const float* __restrict__ a1c, const float* __restrict__ a2c,
    unsigned short* __restrict__ Whb, float* __restrict__ f1, float* __restrict__ f2)
{
    const int tile = blockIdx.x;       // [0, 2048)
    const int tid  = threadIdx.x;
    const int f32  = is_f32(adj);
    const int wv   = tid >> 6;
    const int lane = tid & 63;
    const int nt   = tile >> 3;
    const int h    = tile & 7;
    const int quad = lane >> 4;
    const int l16  = lane & 15;
    const int node = nt * 16 + l16;
    const int kbase = wv * 128 + quad * 8;   // this wave's K-range start + quad offset

    __shared__ float red[3][16][68];   // split-K partials

    f32x4 acc[4];
#pragma unroll
    for (int j = 0; j < 4; ++j) acc[j] = (f32x4){0.f, 0.f, 0.f, 0.f};

    const unsigned short* wp = Wt + (size_t)h * FDIM * DIN + kbase;
    if (f32) {
        const float* xp = (const float*)X + (size_t)node * DIN + kbase;
#pragma unroll
        for (int ks = 0; ks < 4; ++ks) {
            float4 xa = *(const float4*)(xp + ks * 32);
            float4 xb = *(const float4*)(xp + ks * 32 + 4);
            bf16x8 xf;
            xf[0] = (short)f2us(xa.x); xf[1] = (short)f2us(xa.y);
            xf[2] = (short)f2us(xa.z); xf[3] = (short)f2us(xa.w);
            xf[4] = (short)f2us(xb.x); xf[5] = (short)f2us(xb.y);
            xf[6] = (short)f2us(xb.z); xf[7] = (short)f2us(xb.w);
#pragma unroll
            for (int j = 0; j < 4; ++j) {
                bf16x8 wf = *(const bf16x8*)(wp + (size_t)(j * 16 + l16) * DIN + ks * 32);
                acc[j] = __builtin_amdgcn_mfma_f32_16x16x32_bf16(wf, xf, acc[j], 0, 0, 0);
            }
        }
    } else {
        const unsigned short* xp = (const unsigned short*)X + (size_t)node * DIN + kbase;
#pragma unroll
        for (int ks = 0; ks < 4; ++ks) {
            bf16x8 xf = *(const bf16x8*)(xp + ks * 32);
#pragma unroll
            for (int j = 0; j < 4; ++j) {
                bf16x8 wf = *(const bf16x8*)(wp + (size_t)(j * 16 + l16) * DIN + ks * 32);
                acc[j] = __builtin_amdgcn_mfma_f32_16x16x32_bf16(wf, xf, acc[j], 0, 0, 0);
            }
        }
    }

    if (wv) {
#pragma unroll
        for (int j = 0; j < 4; ++j)
            *(f32x4*)&red[wv - 1][l16][j * 16 + quad * 4] = acc[j];
    }
    __syncthreads();
    if (wv == 0) {
        // D layout: col(=node)=l16, row(=f within 16-tile)=quad*4+rr  [m89-verified]
        float p1 = 0.f, p2 = 0.f;
#pragma unroll
        for (int j = 0; j < 4; ++j) {
            const int fbase = j * 16 + quad * 4;
            f32x4 s = acc[j];
#pragma unroll
            for (int p = 0; p < 3; ++p) s += *(const f32x4*)&red[p][l16][fbase];
            ushort4 st;
            st.x = f2us(s[0]); st.y = f2us(s[1]);
            st.z = f2us(s[2]); st.w = f2us(s[3]);
            *(ushort4*)&Whb[((size_t)node * NHEADS + h) * FDIM + fbase] = st;
#pragma unroll
            for (int rr = 0; rr < 4; ++rr) {
                p1 += s[rr] * a1c[h * FDIM + fbase + rr];
                p2 += s[rr] * a2c[h * FDIM + fbase + rr];
            }
        }
        p1 += __shfl_xor(p1, 16); p1 += __shfl_xor(p1, 32);
        p2 += __shfl_xor(p2, 16); p2 += __shfl_xor(p2, 32);
        if (quad == 0) {
            f1[h * N_NODES + node] = p1;
            f2[h * N_NODES + node] = p2;
        }
    }
}

// ---------------------------------------------------------------------------
// K3: attn1 with ONLINE softmax fused into the gather (verified rounds 3-6).
// ---------------------------------------------------------------------------
__global__ __launch_bounds__(256) void attn1_kernel(
    const unsigned short* __restrict__ Whb,
    const float* __restrict__ f1, const float* __restrict__ f2,
    const float* __restrict__ Woc,
    const float* __restrict__ ao1c, const float* __restrict__ ao2c,
    const int* __restrict__ cnt, const int* __restrict__ nbr,
    float* __restrict__ Who, float* __restrict__ g1, float* __restrict__ g2)
{
    const int n   = blockIdx.x;
    const int tid = threadIdx.x;
    const int wv  = tid >> 6;
    const int lane = tid & 63;
    const int hh = lane >> 3;               // head for this lane

    __shared__ int   sh_m[MAXN];            // 2 KB
    __shared__ float sh_red[3][64][9];      // cross-wave acc partials (pad 9)
    __shared__ float sh_ml[4][NHEADS][2];   // per-wave per-head (m_ref, l)
    __shared__ float cat_sh[512];           // fp32 cat row
    __shared__ float sh_p[16 * 17];         // who partials (pad 17)

    const int c0 = cnt[n];
    const int c = (c0 < MAXN) ? c0 : MAXN;
    for (int k = tid; k < c; k += 256) sh_m[k] = nbr[(size_t)n * MAXN + k];
    __syncthreads();

    // ---- gather with online softmax ----
    const float f1v = f1[hh * N_NODES + n];
    float m_run = -1e30f, l_run = 0.f;
    float acc8[8];
#pragma unroll
    for (int e = 0; e < 8; ++e) acc8[e] = 0.f;
    const uint4* wb = (const uint4*)Whb;
#pragma unroll 2
    for (int kb = 0; kb < c; kb += 4) {
        const int k = kb + wv;                  // wave-uniform guard
        if (k < c) {
            const int mm = sh_m[k];
            uint4 v = wb[(size_t)mm * 64 + lane];
            float s = f1v + f2[hh * N_NODES + mm];
            s = (s >= 0.f) ? s : 0.2f * s;      // LeakyReLU(0.2)
            if (s > m_run + 8.f) {              // defer-max: rescale rarely
                float scale = __expf(m_run - s);
                l_run *= scale;
#pragma unroll
                for (int e = 0; e < 8; ++e) acc8[e] *= scale;
                m_run = s;
            }
            float wgt = __expf(s - m_run);      // bounded by e^8
            l_run += wgt;
            acc8[0] += wgt * us2f((unsigned short)(v.x & 0xFFFFu));
            acc8[1] += wgt * us2f((unsigned short)(v.x >> 16));
            acc8[2] += wgt * us2f((unsigned short)(v.y & 0xFFFFu));
            acc8[3] += wgt * us2f((unsigned short)(v.y >> 16));
            acc8[4] += wgt * us2f((unsigned short)(v.z & 0xFFFFu));
            acc8[5] += wgt * us2f((unsigned short)(v.z >> 16));
            acc8[6] += wgt * us2f((unsigned short)(v.w & 0xFFFFu));
            acc8[7] += wgt * us2f((unsigned short)(v.w >> 16));
        }
    }
    if (wv) {
#pragma unroll
        for (int e = 0; e < 8; ++e) sh_red[wv - 1][lane][e] = acc8[e];
    }
    if ((lane & 7) == 0) {
        sh_ml[wv][hh][0] = m_run;
        sh_ml[wv][hh][1] = l_run;
    }
    __syncthreads();
    if (wv == 0) {
        float m1 = sh_ml[1][hh][0], m2 = sh_ml[2][hh][0], m3 = sh_ml[3][hh][0];
        float M = fmaxf(fmaxf(m_run, m1), fmaxf(m2, m3));
        float c0f = __expf(m_run - M), c1f = __expf(m1 - M);
        float c2f = __expf(m2 - M),  c3f = __expf(m3 - M);
        float denom = l_run * c0f + sh_ml[1][hh][1] * c1f
                    + sh_ml[2][hh][1] * c2f + sh_ml[3][hh][1] * c3f;
        const float inv = (denom > 0.f) ? 1.f / denom : 0.f;
#pragma unroll
        for (int e = 0; e < 8; ++e) {
            float s = acc8[e] * c0f + sh_red[0][lane][e] * c1f
                    + sh_red[1][lane][e] * c2f + sh_red[2][lane][e] * c3f;
            s *= inv;
            s = (s > 0.f) ? s : expm1f(s);      // ELU
            cat_sh[lane * 8 + e] = s;           // cat[h*64+f] == lane*8+e (fp32)
        }
    }
    __syncthreads();

    // ---- fused Who = cat @ Wo (fp32, 512x16) + g1/g2 ----
    {
        const int j = tid & 15, ch = tid >> 4;  // 16 chunks x 32 d each
        float s = 0.f;
#pragma unroll
        for (int d = 0; d < 32; ++d)
            s += cat_sh[ch * 32 + d] * Woc[(ch * 32 + d) * DOUT + j];
        sh_p[ch * 17 + j] = s;
    }
    __syncthreads();
    if (tid < 16) {
        float s = 0.f;
#pragma unroll
        for (int ch = 0; ch < 16; ++ch) s += sh_p[ch * 17 + tid];
        Who[n * DOUT + tid] = s;
        float p1 = s * ao1c[tid];
        float p2 = s * ao2c[tid];
#pragma unroll
        for (int off = 8; off; off >>= 1) {
            p1 += __shfl_xor(p1, off);
            p2 += __shfl_xor(p2, off);
        }
        if (tid == 0) { g1[n] = p1; g2[n] = p2; }
    }
}

// ---------------------------------------------------------------------------
// K4: output sparse attention, wave-per-node (verified rounds 5-6).
// ---------------------------------------------------------------------------
__global__ __launch_bounds__(256) void attn2_kernel(
    const void* __restrict__ adj,
    const float* __restrict__ Who,
    const float* __restrict__ g1, const float* __restrict__ g2,
    const int* __restrict__ cnt, const int* __restrict__ nbr,
    void* __restrict__ out)
{
    const int wv   = threadIdx.x >> 6;
    const int lane = threadIdx.x & 63;
    const int n = blockIdx.x * 4 + wv;
    const int quad = lane >> 4, l16 = lane & 15;
    __shared__ float sh_s[4][MAXN];
    __shared__ int   sh_m[4][MAXN];
    const int c0 = cnt[n];
    const int c = (c0 < MAXN) ? c0 : MAXN;
    for (int k = lane; k < c; k += 64) sh_m[wv][k] = nbr[(size_t)n * MAXN + k];
    const float gn = g1[n];
    float mx = -1e30f;
    for (int k = lane; k < c; k += 64) {
        float s = gn + g2[sh_m[wv][k]];
        s = (s >= 0.f) ? s : 0.2f * s;
        sh_s[wv][k] = s;
        mx = fmaxf(mx, s);
    }
#pragma unroll
    for (int off = 32; off; off >>= 1) mx = fmaxf(mx, __shfl_xor(mx, off));
    float sum = 0.f;
    for (int k = lane; k < c; k += 64) {
        float e = __expf(sh_s[wv][k] - mx);
        sh_s[wv][k] = e;
        sum += e;
    }
#pragma unroll
    for (int off = 32; off; off >>= 1) sum += __shfl_xor(sum, off);
    const float inv = (sum > 0.f) ? 1.f / sum : 0.f;
    float accv = 0.f;
#pragma unroll 4
    for (int k = quad; k < c; k += 4)
        accv += sh_s[wv][k] * Who[sh_m[wv][k] * DOUT + l16];
    accv += __shfl_xor(accv, 16);
    accv += __shfl_xor(accv, 32);
    if (quad == 0) {
        float v = accv * inv;
        if (is_f32(adj)) ((float*)out)[n * DOUT + l16] = v;
        else             ((unsigned short*)out)[n * DOUT + l16] = f2us(v);
    }
}

__global__ void wsfail_kernel(float* __restrict__ out)
{
    if (threadIdx.x == 0) out[0] = 129.f;
}

// ---------------------------------------------------------------------------
extern "C" void kernel_launch(void* const* d_in, const int* in_sizes, int n_in,
                              void* d_out, int out_size, void* d_ws, size_t ws_size,
                              hipStream_t stream)
{
    const void* adj = d_in[0];
    const void* X   = d_in[1];
    const void* W   = d_in[2];
    const void* a1  = d_in[3];
    const void* a2  = d_in[4];
    const void* Wo  = d_in[5];
    const void* ao1 = d_in[6];
    const void* ao2 = d_in[7];

    const size_t NEEDED = 22000000;
    if (ws_size < NEEDED) { wsfail_kernel<<<1, 64, 0, stream>>>((float*)d_out); return; }

    int*   cnt  = (int*)d_ws;                        // 4096
    int*   nbr  = cnt + 4096;                        // 4096*512
    float* a1c  = (float*)(nbr + 2097152);           // 512
    float* a2c  = a1c + 512;                         // 512
    float* ao1c = a2c + 512;                         // 16
    float* ao2c = ao1c + 16;                         // 16
    float* f1   = ao2c + 16;                         // 32768
    float* f2   = f1 + 32768;                        // 32768
    float* Who  = f2 + 32768;                        // 65536
    float* g1   = Who + 65536;                       // 4096
    float* g2   = g1 + 4096;                         // 4096
    float* Woc  = g2 + 4096;                         // 8192
    unsigned short* Whb = (unsigned short*)(Woc + 8192);  // 2097152
    unsigned short* Wt  = Whb + 2097152;                  // 262144

    scan_kernel<<<N_NODES / 4, 256, 0, stream>>>(adj, cnt, nbr);
    prep_kernel<<<72, 256, 0, stream>>>(
        adj, W, a1, a2, Wo, ao1, ao2, Wt, Woc, a1c, a2c, ao1c, ao2c);
    wh_kernel<<<2048, 256, 0, stream>>>(
        adj, X, Wt, a1c, a2c, Whb, f1, f2);
    attn1_kernel<<<N_NODES, 256, 0, stream>>>(
        Whb, f1, f2, Woc, ao1c, ao2c, cnt, nbr, Who, g1, g2);
    attn2_kernel<<<N_NODES / 4, 256, 0, stream>>>(adj, Who, g1, g2, cnt, nbr, d_out);
}

// Round 8
// 163.628 us; speedup vs baseline: 1.0311x; 1.0311x over previous
//
#include <hip/hip_runtime.h>
#include <hip/hip_bf16.h>

#define N_NODES 4096
#define DIN     512
#define FDIM    64
#define NHEADS  8
#define DOUT    16
#define MAXN    512

typedef __attribute__((ext_vector_type(8))) short bf16x8;
typedef __attribute__((ext_vector_type(4))) float f32x4;

static __device__ __forceinline__ float us2f(unsigned short u) {
    union { unsigned int i; float f; } cv; cv.i = ((unsigned int)u) << 16; return cv.f;
}
static __device__ __forceinline__ unsigned short f2us(float v) {
    __hip_bfloat16 b = __float2bfloat16(v);
    return *(const unsigned short*)&b;
}
// dtype: adj[0][0] is a guaranteed self-loop 1.0; fp32 1.0f low ushort = 0 (verified r4-r11)
static __device__ __forceinline__ int is_f32(const void* adj) {
    return (((const unsigned short*)adj)[0] == 0) ? 1 : 0;
}

// ---------------------------------------------------------------------------
// K0: ballot scan, HALF-ROW PER WAVE at full occupancy.
// 2048 blocks x 4 waves = 2 rows/block, 2 waves/row; __launch_bounds__(256,8)
// forces VGPR<=64 so 8 waves/SIMD (32 waves/CU) are resident — r5-r7 ran at
// 16 waves/CU (VGPR=68 > 64 boundary) with a 64-component serial ballot chain
// per wave; this halves the chain and doubles the latency-hiding wave pool.
// Halves compact into LDS; one barrier; concatenated writeout (order-preserving).
// ---------------------------------------------------------------------------
__global__ __launch_bounds__(256, 8) void scan_kernel(
    const void* __restrict__ adj, int* __restrict__ cnt, int* __restrict__ nbr)
{
    const int wv   = threadIdx.x >> 6;     // 0..3
    const int lane = threadIdx.x & 63;
    const int rib  = wv >> 1;              // row within block: 0/1
    const int half = wv & 1;               // which half of the row
    const int n    = blockIdx.x * 2 + rib;
    const unsigned long long lmask = (1ull << lane) - 1ull;

    __shared__ int buf[2][2][516];         // [row][half][pos], ~8.3 KB
    __shared__ int sc[2][2];

    int c = 0;
    if (is_f32(adj)) {
        const uint4* row = (const uint4*)((const unsigned int*)adj + (size_t)n * N_NODES);
#pragma unroll
        for (int batch = 0; batch < 2; ++batch) {
            uint4 vb[4];
#pragma unroll
            for (int i = 0; i < 4; ++i)
                vb[i] = row[half * 512 + (batch * 4 + i) * 64 + lane];
#pragma unroll
            for (int i = 0; i < 4; ++i) {
                uint4 v = vb[i];
                int base = (half * 512 + (batch * 4 + i) * 64 + lane) * 4;
                unsigned long long m0 = __ballot(v.x != 0u);
                unsigned long long m1 = __ballot(v.y != 0u);
                unsigned long long m2 = __ballot(v.z != 0u);
                unsigned long long m3 = __ballot(v.w != 0u);
                int p;
                p = c + __popcll(m0 & lmask); if (v.x && p < 512) buf[rib][half][p] = base + 0; c += __popcll(m0);
                p = c + __popcll(m1 & lmask); if (v.y && p < 512) buf[rib][half][p] = base + 1; c += __popcll(m1);
                p = c + __popcll(m2 & lmask); if (v.z && p < 512) buf[rib][half][p] = base + 2; c += __popcll(m2);
                p = c + __popcll(m3 & lmask); if (v.w && p < 512) buf[rib][half][p] = base + 3; c += __popcll(m3);
            }
        }
    } else {
        const ushort4* row = (const ushort4*)((const unsigned short*)adj + (size_t)n * N_NODES);
#pragma unroll
        for (int batch = 0; batch < 2; ++batch) {
            ushort4 vb[4];
#pragma unroll
            for (int i = 0; i < 4; ++i)
                vb[i] = row[half * 512 + (batch * 4 + i) * 64 + lane];
#pragma unroll
            for (int i = 0; i < 4; ++i) {
                ushort4 v = vb[i];
                int base = (half * 512 + (batch * 4 + i) * 64 + lane) * 4;
                unsigned long long m0 = __ballot(v.x != 0);
                unsigned long long m1 = __ballot(v.y != 0);
                unsigned long long m2 = __ballot(v.z != 0);
                unsigned long long m3 = __ballot(v.w != 0);
                int p;
                p = c + __popcll(m0 & lmask); if (v.x && p < 512) buf[rib][half][p] = base + 0; c += __popcll(m0);
                p = c + __popcll(m1 & lmask); if (v.y && p < 512) buf[rib][half][p] = base + 1; c += __popcll(m1);
                p = c + __popcll(m2 & lmask); if (v.z && p < 512) buf[rib][half][p] = base + 2; c += __popcll(m2);
                p = c + __popcll(m3 & lmask); if (v.w && p < 512) buf[rib][half][p] = base + 3; c += __popcll(m3);
            }
        }
    }
    if (lane == 0) sc[rib][half] = (c < 512) ? c : 512;
    __syncthreads();

    // writeout: the row's 2 waves (128 lanes) concatenate half0 ++ half1
    const int c0 = sc[rib][0];
    const int c1 = sc[rib][1];
    int ctot = c0 + c1; if (ctot > MAXN) ctot = MAXN;
    int* nrow = nbr + (size_t)n * MAXN;
    const int tr = half * 64 + lane;       // 0..127 within the row pair
    for (int j = tr; j < ctot; j += 128)
        nrow[j] = (j < c0) ? buf[rib][0][j] : buf[rib][1][j - c0];
    if (tr == 0) cnt[n] = ctot;
}

// ---------------------------------------------------------------------------
// K1: prep. Blocks 0..63: W -> Wt[h][f][d] bf16 via LDS 64x64 tile transpose.
// Blocks 64..71: Woc/vecs. (verified r5-r7)
// ---------------------------------------------------------------------------
__global__ __launch_bounds__(256) void prep_kernel(
    const void* __restrict__ adj, const void* __restrict__ W,
    const void* __restrict__ a1, const void* __restrict__ a2, const void* __restrict__ Wo,
    const void* __restrict__ ao1, const void* __restrict__ ao2,
    unsigned short* __restrict__ Wt, float* __restrict__ Woc,
    float* __restrict__ a1c, float* __restrict__ a2c,
    float* __restrict__ ao1c, float* __restrict__ ao2c)
{
    const int f32 = is_f32(adj);
    const int b = blockIdx.x;
    const int t = threadIdx.x;
    if (b < 64) {
        const int h  = b >> 3;
        const int d0 = (b & 7) * 64;
        __shared__ float tile[64][65];
        const size_t wbase = (size_t)h * DIN * FDIM + (size_t)d0 * FDIM;
#pragma unroll
        for (int pass = 0; pass < 16; ++pass) {
            int i = pass * 256 + t;
            int dl = i >> 6, f = i & 63;
            float v = f32 ? ((const float*)W)[wbase + dl * FDIM + f]
                          : us2f(((const unsigned short*)W)[wbase + dl * FDIM + f]);
            tile[dl][f] = v;
        }
        __syncthreads();
#pragma unroll
        for (int pass = 0; pass < 16; ++pass) {
            int i = pass * 256 + t;
            int f = i >> 6, dl = i & 63;
            Wt[((size_t)(h * FDIM + f)) * DIN + d0 + dl] = f2us(tile[dl][f]);
        }
        return;
    }
    const int i0 = (b - 64) * 256 + t;   // [0, 2048)
    for (int i = i0; i < DIN * DOUT; i += 2048) {
        float v = f32 ? ((const float*)Wo)[i] : us2f(((const unsigned short*)Wo)[i]);
        Woc[i] = v;   // row-major [d][j], fp32
    }
    if (i0 < 512) {
        a1c[i0] = f32 ? ((const float*)a1)[i0] : us2f(((const unsigned short*)a1)[i0]);
        a2c[i0] = f32 ? ((const float*)a2)[i0] : us2f(((const unsigned short*)a2)[i0]);
    }
    if (i0 < 16) {
        ao1c[i0] = f32 ? ((const float*)ao1)[i0] : us2f(((const unsigned short*)ao1)[i0]);
        ao2c[i0] = f32 ? ((const float*)ao2)[i0] : us2f(((const unsigned short*)ao2)[i0]);
    }
}

// ---------------------------------------------------------------------------
// K2: split-K MFMA wh (2048 blocks; math verified r4-r7).
// ---------------------------------------------------------------------------
__global__ __launch_bounds__(256) void wh_kernel(
    const void* __restrict__ adj, const void* __restrict__ X,
    const unsigned short* __restrict__ Wt,
    const float* __restrict__ a1c, const float* __restrict__ a2c,
    unsigned short* __restrict__ Whb, float* __restrict__ f1, float* __restrict__ f2)
{
    const int tile = blockIdx.x;       // [0, 2048)
    const int tid  = threadIdx.x;
    const int f32  = is_f32(adj);
    const int wv   = tid >> 6;
    const int lane = tid & 63;
    const int nt   = tile >> 3;
    const int h    = tile & 7;
    const int quad = lane >> 4;
    const int l16  = lane & 15;
    const int node = nt * 16 + l16;
    const int kbase = wv * 128 + quad * 8;   // this wave's K-range start + quad offset

    __shared__ float red[3][16][68];   // split-K partials

    f32x4 acc[4];
#pragma unroll
    for (int j = 0; j < 4; ++j) acc[j] = (f32x4){0.f, 0.f, 0.f, 0.f};

    const unsigned short* wp = Wt + (size_t)h * FDIM * DIN + kbase;
    if (f32) {
        const float* xp = (const float*)X + (size_t)node * DIN + kbase;
#pragma unroll
        for (int ks = 0; ks < 4; ++ks) {
            float4 xa = *(const float4*)(xp + ks * 32);
            float4 xb = *(const float4*)(xp + ks * 32 + 4);
            bf16x8 xf;
            xf[0] = (short)f2us(xa.x); xf[1] = (short)f2us(xa.y);
            xf[2] = (short)f2us(xa.z); xf[3] = (short)f2us(xa.w);
            xf[4] = (short)f2us(xb.x); xf[5] = (short)f2us(xb.y);
            xf[6] = (short)f2us(xb.z); xf[7] = (short)f2us(xb.w);
#pragma unroll
            for (int j = 0; j < 4; ++j) {
                bf16x8 wf = *(const bf16x8*)(wp + (size_t)(j * 16 + l16) * DIN + ks * 32);
                acc[j] = __builtin_amdgcn_mfma_f32_16x16x32_bf16(wf, xf, acc[j], 0, 0, 0);
            }
        }
    } else {
        const unsigned short* xp = (const unsigned short*)X + (size_t)node * DIN + kbase;
#pragma unroll
        for (int ks = 0; ks < 4; ++ks) {
            bf16x8 xf = *(const bf16x8*)(xp + ks * 32);
#pragma unroll
            for (int j = 0; j < 4; ++j) {
                bf16x8 wf = *(const bf16x8*)(wp + (size_t)(j * 16 + l16) * DIN + ks * 32);
                acc[j] = __builtin_amdgcn_mfma_f32_16x16x32_bf16(wf, xf, acc[j], 0, 0, 0);
            }
        }
    }

    if (wv) {
#pragma unroll
        for (int j = 0; j < 4; ++j)
            *(f32x4*)&red[wv - 1][l16][j * 16 + quad * 4] = acc[j];
    }
    __syncthreads();
    if (wv == 0) {
        // D layout: col(=node)=l16, row(=f within 16-tile)=quad*4+rr  [m89-verified]
        float p1 = 0.f, p2 = 0.f;
#pragma unroll
        for (int j = 0; j < 4; ++j) {
            const int fbase = j * 16 + quad * 4;
            f32x4 s = acc[j];
#pragma unroll
            for (int p = 0; p < 3; ++p) s += *(const f32x4*)&red[p][l16][fbase];
            ushort4 st;
            st.x = f2us(s[0]); st.y = f2us(s[1]);
            st.z = f2us(s[2]); st.w = f2us(s[3]);
            *(ushort4*)&Whb[((size_t)node * NHEADS + h) * FDIM + fbase] = st;
#pragma unroll
            for (int rr = 0; rr < 4; ++rr) {
                p1 += s[rr] * a1c[h * FDIM + fbase + rr];
                p2 += s[rr] * a2c[h * FDIM + fbase + rr];
            }
        }
        p1 += __shfl_xor(p1, 16); p1 += __shfl_xor(p1, 32);
        p2 += __shfl_xor(p2, 16); p2 += __shfl_xor(p2, 32);
        if (quad == 0) {
            f1[h * N_NODES + node] = p1;
            f2[h * N_NODES + node] = p2;
        }
    }
}

// ---------------------------------------------------------------------------
// K3: attn1 with ONLINE softmax fused into the gather (verified rounds 3-7).
// ---------------------------------------------------------------------------
__global__ __launch_bounds__(256) void attn1_kernel(
    const unsigned short* __restrict__ Whb,
    const float* __restrict__ f1, const float* __restrict__ f2,
    const float* __restrict__ Woc,
    const float* __restrict__ ao1c, const float* __restrict__ ao2c,
    const int* __restrict__ cnt, const int* __restrict__ nbr,
    float* __restrict__ Who, float* __restrict__ g1, float* __restrict__ g2)
{
    const int n   = blockIdx.x;
    const int tid = threadIdx.x;
    const int wv  = tid >> 6;
    const int lane = tid & 63;
    const int hh = lane >> 3;               // head for this lane

    __shared__ int   sh_m[MAXN];            // 2 KB
    __shared__ float sh_red[3][64][9];      // cross-wave acc partials (pad 9)
    __shared__ float sh_ml[4][NHEADS][2];   // per-wave per-head (m_ref, l)
    __shared__ float cat_sh[512];           // fp32 cat row
    __shared__ float sh_p[16 * 17];         // who partials (pad 17)

    const int c0 = cnt[n];
    const int c = (c0 < MAXN) ? c0 : MAXN;
    for (int k = tid; k < c; k += 256) sh_m[k] = nbr[(size_t)n * MAXN + k];
    __syncthreads();

    // ---- gather with online softmax ----
    const float f1v = f1[hh * N_NODES + n];
    float m_run = -1e30f, l_run = 0.f;
    float acc8[8];
#pragma unroll
    for (int e = 0; e < 8; ++e) acc8[e] = 0.f;
    const uint4* wb = (const uint4*)Whb;
#pragma unroll 2
    for (int kb = 0; kb < c; kb += 4) {
        const int k = kb + wv;                  // wave-uniform guard
        if (k < c) {
            const int mm = sh_m[k];
            uint4 v = wb[(size_t)mm * 64 + lane];
            float s = f1v + f2[hh * N_NODES + mm];
            s = (s >= 0.f) ? s : 0.2f * s;      // LeakyReLU(0.2)
            if (s > m_run + 8.f) {              // defer-max: rescale rarely
                float scale = __expf(m_run - s);
                l_run *= scale;
#pragma unroll
                for (int e = 0; e < 8; ++e) acc8[e] *= scale;
                m_run = s;
            }
            float wgt = __expf(s - m_run);      // bounded by e^8
            l_run += wgt;
            acc8[0] += wgt * us2f((unsigned short)(v.x & 0xFFFFu));
            acc8[1] += wgt * us2f((unsigned short)(v.x >> 16));
            acc8[2] += wgt * us2f((unsigned short)(v.y & 0xFFFFu));
            acc8[3] += wgt * us2f((unsigned short)(v.y >> 16));
            acc8[4] += wgt * us2f((unsigned short)(v.z & 0xFFFFu));
            acc8[5] += wgt * us2f((unsigned short)(v.z >> 16));
            acc8[6] += wgt * us2f((unsigned short)(v.w & 0xFFFFu));
            acc8[7] += wgt * us2f((unsigned short)(v.w >> 16));
        }
    }
    if (wv) {
#pragma unroll
        for (int e = 0; e < 8; ++e) sh_red[wv - 1][lane][e] = acc8[e];
    }
    if ((lane & 7) == 0) {
        sh_ml[wv][hh][0] = m_run;
        sh_ml[wv][hh][1] = l_run;
    }
    __syncthreads();
    if (wv == 0) {
        float m1 = sh_ml[1][hh][0], m2 = sh_ml[2][hh][0], m3 = sh_ml[3][hh][0];
        float M = fmaxf(fmaxf(m_run, m1), fmaxf(m2, m3));
        float c0f = __expf(m_run - M), c1f = __expf(m1 - M);
        float c2f = __expf(m2 - M),  c3f = __expf(m3 - M);
        float denom = l_run * c0f + sh_ml[1][hh][1] * c1f
                    + sh_ml[2][hh][1] * c2f + sh_ml[3][hh][1] * c3f;
        const float inv = (denom > 0.f) ? 1.f / denom : 0.f;
#pragma unroll
        for (int e = 0; e < 8; ++e) {
            float s = acc8[e] * c0f + sh_red[0][lane][e] * c1f
                    + sh_red[1][lane][e] * c2f + sh_red[2][lane][e] * c3f;
            s *= inv;
            s = (s > 0.f) ? s : expm1f(s);      // ELU
            cat_sh[lane * 8 + e] = s;           // cat[h*64+f] == lane*8+e (fp32)
        }
    }
    __syncthreads();

    // ---- fused Who = cat @ Wo (fp32, 512x16) + g1/g2 ----
    {
        const int j = tid & 15, ch = tid >> 4;  // 16 chunks x 32 d each
        float s = 0.f;
#pragma unroll
        for (int d = 0; d < 32; ++d)
            s += cat_sh[ch * 32 + d] * Woc[(ch * 32 + d) * DOUT + j];
        sh_p[ch * 17 + j] = s;
    }
    __syncthreads();
    if (tid < 16) {
        float s = 0.f;
#pragma unroll
        for (int ch = 0; ch < 16; ++ch) s += sh_p[ch * 17 + tid];
        Who[n * DOUT + tid] = s;
        float p1 = s * ao1c[tid];
        float p2 = s * ao2c[tid];
#pragma unroll
        for (int off = 8; off; off >>= 1) {
            p1 += __shfl_xor(p1, off);
            p2 += __shfl_xor(p2, off);
        }
        if (tid == 0) { g1[n] = p1; g2[n] = p2; }
    }
}

// ---------------------------------------------------------------------------
// K4: output sparse attention, wave-per-node (verified rounds 5-7).
// ---------------------------------------------------------------------------
__global__ __launch_bounds__(256) void attn2_kernel(
    const void* __restrict__ adj,
    const float* __restrict__ Who,
    const float* __restrict__ g1, const float* __restrict__ g2,
    const int* __restrict__ cnt, const int* __restrict__ nbr,
    void* __restrict__ out)
{
    const int wv   = threadIdx.x >> 6;
    const int lane = threadIdx.x & 63;
    const int n = blockIdx.x * 4 + wv;
    const int quad = lane >> 4, l16 = lane & 15;
    __shared__ float sh_s[4][MAXN];
    __shared__ int   sh_m[4][MAXN];
    const int c0 = cnt[n];
    const int c = (c0 < MAXN) ? c0 : MAXN;
    for (int k = lane; k < c; k += 64) sh_m[wv][k] = nbr[(size_t)n * MAXN + k];
    const float gn = g1[n];
    float mx = -1e30f;
    for (int k = lane; k < c; k += 64) {
        float s = gn + g2[sh_m[wv][k]];
        s = (s >= 0.f) ? s : 0.2f * s;
        sh_s[wv][k] = s;
        mx = fmaxf(mx, s);
    }
#pragma unroll
    for (int off = 32; off; off >>= 1) mx = fmaxf(mx, __shfl_xor(mx, off));
    float sum = 0.f;
    for (int k = lane; k < c; k += 64) {
        float e = __expf(sh_s[wv][k] - mx);
        sh_s[wv][k] = e;
        sum += e;
    }
#pragma unroll
    for (int off = 32; off; off >>= 1) sum += __shfl_xor(sum, off);
    const float inv = (sum > 0.f) ? 1.f / sum : 0.f;
    float accv = 0.f;
#pragma unroll 4
    for (int k = quad; k < c; k += 4)
        accv += sh_s[wv][k] * Who[sh_m[wv][k] * DOUT + l16];
    accv += __shfl_xor(accv, 16);
    accv += __shfl_xor(accv, 32);
    if (quad == 0) {
        float v = accv * inv;
        if (is_f32(adj)) ((float*)out)[n * DOUT + l16] = v;
        else             ((unsigned short*)out)[n * DOUT + l16] = f2us(v);
    }
}

__global__ void wsfail_kernel(float* __restrict__ out)
{
    if (threadIdx.x == 0) out[0] = 129.f;
}

// ---------------------------------------------------------------------------
extern "C" void kernel_launch(void* const* d_in, const int* in_sizes, int n_in,
                              void* d_out, int out_size, void* d_ws, size_t ws_size,
                              hipStream_t stream)
{
    const void* adj = d_in[0];
    const void* X   = d_in[1];
    const void* W   = d_in[2];
    const void* a1  = d_in[3];
    const void* a2  = d_in[4];
    const void* Wo  = d_in[5];
    const void* ao1 = d_in[6];
    const void* ao2 = d_in[7];

    const size_t NEEDED = 22000000;
    if (ws_size < NEEDED) { wsfail_kernel<<<1, 64, 0, stream>>>((float*)d_out); return; }

    int*   cnt  = (int*)d_ws;                        // 4096
    int*   nbr  = cnt + 4096;                        // 4096*512
    float* a1c  = (float*)(nbr + 2097152);           // 512
    float* a2c  = a1c + 512;                         // 512
    float* ao1c = a2c + 512;                         // 16
    float* ao2c = ao1c + 16;                         // 16
    float* f1   = ao2c + 16;                         // 32768
    float* f2   = f1 + 32768;                        // 32768
    float* Who  = f2 + 32768;                        // 65536
    float* g1   = Who + 65536;                       // 4096
    float* g2   = g1 + 4096;                         // 4096
    float* Woc  = g2 + 4096;                         // 8192
    unsigned short* Whb = (unsigned short*)(Woc + 8192);  // 2097152
    unsigned short* Wt  = Whb + 2097152;                  // 262144

    scan_kernel<<<N_NODES / 2, 256, 0, stream>>>(adj, cnt, nbr);
    prep_kernel<<<72, 256, 0, stream>>>(
        adj, W, a1, a2, Wo, ao1, ao2, Wt, Woc, a1c, a2c, ao1c, ao2c);
    wh_kernel<<<2048, 256, 0, stream>>>(
        adj, X, Wt, a1c, a2c, Whb, f1, f2);
    attn1_kernel<<<N_NODES, 256, 0, stream>>>(
        Whb, f1, f2, Woc, ao1c, ao2c, cnt, nbr, Who, g1, g2);
    attn2_kernel<<<N_NODES / 4, 256, 0, stream>>>(adj, Who, g1, g2, cnt, nbr, d_out);
}